// Round 8
// baseline (335.370 us; speedup 1.0000x reference)
//
#include <hip/hip_runtime.h>

typedef __attribute__((ext_vector_type(4))) float f32x4;
typedef __attribute__((ext_vector_type(8))) short s16x8;

__device__ __forceinline__ float bf2f(short b) {
  unsigned int u = ((unsigned int)(unsigned short)b) << 16;
  return __builtin_bit_cast(float, u);
}
__device__ __forceinline__ short f2bf(float f) {
  unsigned int u = __builtin_bit_cast(unsigned int, f);
  u = (u + 0x7fffu + ((u >> 16) & 1u)) >> 16;
  return (short)u;
}
__device__ __forceinline__ unsigned cvt_pk_bf16(float a, float b) {
  unsigned r;
  asm("v_cvt_pk_bf16_f32 %0, %1, %2" : "=v"(r) : "v"(a), "v"(b));
  return r;
}

__device__ __forceinline__ void async_copy16(void* lds, const void* g) {
  __builtin_amdgcn_global_load_lds((const __attribute__((address_space(1))) unsigned int*)g,
                                   (__attribute__((address_space(3))) unsigned int*)lds,
                                   16, 0, 0);
}

// ---------------- pack kernels ----------------

__global__ __launch_bounds__(256) void cvt_f32_bf16(const float* __restrict__ src,
                                                    short* __restrict__ dst, int n) {
  const int i = (blockIdx.x * 256 + threadIdx.x) * 4;
  if (i >= n) return;
  const float4 v = *(const float4*)&src[i];
  short4 o;
  o.x = f2bf(v.x); o.y = f2bf(v.y); o.z = f2bf(v.z); o.w = f2bf(v.w);
  *(short4*)&dst[i] = o;
}

// src fp32 [R][C] -> dst bf16 [C][R]
__global__ __launch_bounds__(256) void transpose_cvt(const float* __restrict__ src,
                                                     short* __restrict__ dst, int R, int C) {
  __shared__ float t[32][33];
  const int c0 = blockIdx.x * 32, r0 = blockIdx.y * 32;
  const int tx = threadIdx.x & 31;
  const int ty = threadIdx.x >> 5;  // 0..7
#pragma unroll
  for (int i = 0; i < 4; ++i)
    t[ty + 8 * i][tx] = src[(size_t)(r0 + ty + 8 * i) * C + c0 + tx];
  __syncthreads();
#pragma unroll
  for (int i = 0; i < 4; ++i)
    dst[(size_t)(c0 + ty + 8 * i) * R + r0 + tx] = f2bf(t[tx][ty + 8 * i]);
}

// bf16 V slice of qkv [B*2048][3072] -> vt [B][512][2048], kv natural order,
// XOR-swizzled by d (^((d&7)<<3)) within each 64-kv block.
__global__ __launch_bounds__(256) void transpose_v(const short* __restrict__ qkv,
                                                   short* __restrict__ vt) {
  __shared__ short t[32][33];
  const int l0 = blockIdx.x * 32;  // L tile
  const int c0 = blockIdx.y * 32;  // col within 512
  const int b = blockIdx.z;
  const int tx = threadIdx.x & 31, ty = threadIdx.x >> 5;
#pragma unroll
  for (int i = 0; i < 4; ++i)
    t[ty + 8 * i][tx] = qkv[(size_t)(b * 2048 + l0 + ty + 8 * i) * 3072 + 2560 + c0 + tx];
  __syncthreads();
#pragma unroll
  for (int i = 0; i < 4; ++i) {
    const int c = c0 + ty + 8 * i;     // d within 512 (head-aligned: swz uses d&7)
    const int l = l0 + tx;
    const int kvp = (l & 63) ^ ((c & 7) << 3);
    vt[((size_t)b * 512 + c) * 2048 + (l & ~63) + kvp] = t[tx][ty + 8 * i];
  }
}

// ---------------- GEMM: C[M][N] = A[M][K] * BT[N][K]^T ----------------

template <bool OUT_BF16>
__global__ __launch_bounds__(256) void gemm_bt(const short* __restrict__ A,
                                               const short* __restrict__ BT,
                                               void* __restrict__ Cout,
                                               int M, int N, int K) {
  __shared__ short As[128 * 32];
  __shared__ short Bs[128 * 32];
  const int tid = threadIdx.x;
  const int l = tid & 63, wid = tid >> 6;
  const int m0 = blockIdx.x * 128, n0 = blockIdx.y * 128;
  const int wr = (wid >> 1) * 64, wc = (wid & 1) * 64;
  const int lr = l & 15, lc = l >> 4;
  f32x4 acc[4][4] = {};

  for (int k0 = 0; k0 < K; k0 += 32) {
    __syncthreads();
#pragma unroll
    for (int i = 0; i < 2; ++i) {
      const int c = tid + 256 * i;
      const int row = c >> 2, kc = (c & 3) * 8;
      async_copy16((char*)As + (size_t)(i * 256 + wid * 64) * 16,
                   A + (size_t)(m0 + row) * K + k0 + kc);
      async_copy16((char*)Bs + (size_t)(i * 256 + wid * 64) * 16,
                   BT + (size_t)(n0 + row) * K + k0 + kc);
    }
    __syncthreads();
    s16x8 a[4], b[4];
#pragma unroll
    for (int m = 0; m < 4; ++m)
      a[m] = *(const s16x8*)&As[(wr + m * 16 + lr) * 32 + lc * 8];
#pragma unroll
    for (int n = 0; n < 4; ++n)
      b[n] = *(const s16x8*)&Bs[(wc + n * 16 + lr) * 32 + lc * 8];
#pragma unroll
    for (int m = 0; m < 4; ++m)
#pragma unroll
      for (int n = 0; n < 4; ++n)
        acc[m][n] = __builtin_amdgcn_mfma_f32_16x16x32_bf16(a[m], b[n], acc[m][n], 0, 0, 0);
  }

#pragma unroll
  for (int m = 0; m < 4; ++m)
#pragma unroll
    for (int n = 0; n < 4; ++n)
#pragma unroll
      for (int r = 0; r < 4; ++r) {
        const size_t row = (size_t)(m0 + wr + m * 16 + lc * 4 + r);
        const int col = n0 + wc + n * 16 + lr;
        if constexpr (OUT_BF16)
          ((short*)Cout)[row * N + col] = f2bf(acc[m][n][r]);
        else
          ((float*)Cout)[row * N + col] = acc[m][n][r];
      }
}

// ---------------- RoPE ----------------
// Q: in-place on qkv [4096][3072]. K: written to kswz [B][4][2048][128] with
// d-index XOR-swizzled (^((l&7)<<3)) so flash_attn can global_load_lds it linearly.

__global__ __launch_bounds__(256) void rope_kernel(short* __restrict__ qkv,
                                                   short* __restrict__ kswz,
                                                   const float* __restrict__ cosb,
                                                   const float* __restrict__ sinb) {
  const int idx = blockIdx.x * 256 + threadIdx.x;  // 4096*20*64 threads
  const int d = idx & 63;
  const int hh = (idx >> 6) % 20;
  const int row = idx / (64 * 20);
  const int lpos = row & 2047;
  const int col = (hh < 16) ? hh * 128 + d : 2048 + (hh - 16) * 128 + d;
  short* p = qkv + (size_t)row * 3072 + col;
  const float x1 = bf2f(p[0]);
  const float x2 = bf2f(p[64]);
  const float c = cosb[lpos * 128 + d];
  const float sn = sinb[lpos * 128 + d];
  const short o1 = f2bf(x1 * c - x2 * sn);
  const short o2 = f2bf(x2 * c + x1 * sn);
  if (hh < 16) {
    p[0] = o1;
    p[64] = o2;
  } else {
    const int b = row >> 11;
    const int kvh = hh - 16;
    short* kp = kswz + (((size_t)(b * 4 + kvh) * 2048) + lpos) * 128;
    const int sw = (lpos & 7) << 3;
    kp[d ^ sw] = o1;
    kp[(d + 64) ^ sw] = o2;
  }
}

// ---------------- flash attention (causal, GQA 16/4, hd=128) ----------------
// Block = 2 paired q-tiles (qt, 31-qt) of 64 rows -> 33 KV tiles/block, uniform.
// 4 waves x 16 q-rows. KV tile = 64. Double-buffered K/V staged via
// global_load_lds; prefetch tile t+1 while computing t; counted vmcnt(8) +
// RAW s_barrier (never drain prefetch). Swapped QK^T, lane-local softmax,
// ones-column MFMA row-sum, defer-max, Pb pitch-17 (bank floor).

__global__ __launch_bounds__(256) void flash_attn(const short* __restrict__ qkv,
                                                  const short* __restrict__ kswz,
                                                  const short* __restrict__ vt,
                                                  short* __restrict__ attn_out) {
  __shared__ short Ks[2][64 * 128];   // [kv][d^((kv&7)<<3)]
  __shared__ short Vs[2][128 * 64];   // [d][kv^((d&7)<<3)]
  __shared__ uint2 Pb[4][16][17];     // per-wave P: [q][pair], pitch 17 = b64 bank floor
  const int tid = threadIdx.x;
  const int l = tid & 63, w = tid >> 6;
  const int lr = l & 15, lc = l >> 4;
  const int sw = (lr & 7) << 3;
  const int qpair = blockIdx.x, h = blockIdx.y, b = blockIdx.z;
  const int kvh = h >> 2;
  const short* Qg = qkv + (size_t)b * 2048 * 3072 + h * 128;
  const short* Kg = kswz + ((size_t)(b * 4 + kvh) * 2048) * 128;
  const short* Vtg = vt + ((size_t)b * 512 + kvh * 128) * 2048;
  const float SCALE2 = 0.12751744166306968f;  // hd^-0.5 * log2(e)
  s16x8 ones;
#pragma unroll
  for (int j = 0; j < 8; ++j) ones[j] = (short)0x3F80;  // bf16 1.0

  // loop-invariant staging source bases (per lane)
  const short* kbase[4];
  const short* vbase[4];
#pragma unroll
  for (int i = 0; i < 4; ++i) {
    kbase[i] = Kg + i * 2048 + w * 512 + l * 8;
    vbase[i] = Vtg + (size_t)(i * 32 + w * 8 + (l >> 3)) * 2048 + (l & 7) * 8;
  }

#pragma unroll 1
  for (int seg = 0; seg < 2; ++seg) {
    const int qt = seg ? (31 - qpair) : qpair;
    const int qbase = qt * 64 + w * 16;
    const int nkt = qt + 1;

    // prologue: stage tile 0 into buf 0 (8 loads/thread)
#pragma unroll
    for (int i = 0; i < 4; ++i) {
      async_copy16((char*)Ks[0] + i * 4096 + w * 1024, kbase[i]);
      async_copy16((char*)Vs[0] + i * 4096 + w * 1024, vbase[i]);
    }

    s16x8 qf[4];
#pragma unroll
    for (int dc = 0; dc < 4; ++dc) {
      qf[dc] = *(const s16x8*)&Qg[(size_t)(qbase + lr) * 3072 + dc * 32 + lc * 8];
#pragma unroll
      for (int j = 0; j < 8; ++j) qf[dc][j] = f2bf(bf2f(qf[dc][j]) * SCALE2);
    }

    f32x4 oacc[8] = {};
    f32x4 osum = {0.f, 0.f, 0.f, 0.f};
    float mrow = -__builtin_inff();

#pragma unroll 1
    for (int kt = 0; kt < nkt; ++kt) {
      const int buf = kt & 1;
      const int kv0 = kt * 64;
      if (kt + 1 < nkt) {
        // prefetch next tile into the other buffer
        const int nkv0 = kv0 + 64;
#pragma unroll
        for (int i = 0; i < 4; ++i) {
          async_copy16((char*)Ks[buf ^ 1] + i * 4096 + w * 1024, kbase[i] + (size_t)nkv0 * 128);
          async_copy16((char*)Vs[buf ^ 1] + i * 4096 + w * 1024, vbase[i] + nkv0);
        }
        asm volatile("s_waitcnt vmcnt(8)" ::: "memory");  // tile t landed; t+1 in flight
      } else {
        asm volatile("s_waitcnt vmcnt(0)" ::: "memory");
      }
      __builtin_amdgcn_sched_barrier(0);
      __builtin_amdgcn_s_barrier();   // RAW barrier: do not drain prefetch

      const short* KsB = Ks[buf];
      const short* VsB = Vs[buf];

      // swapped QK^T: S^T[kv][q]; lane (lr,lc) holds q=lr, kv slots cb*16+lc*4+r
      f32x4 sacc[4] = {};
      __builtin_amdgcn_s_setprio(1);
#pragma unroll
      for (int cb = 0; cb < 4; ++cb)
#pragma unroll
        for (int dc = 0; dc < 4; ++dc) {
          const s16x8 kf = *(const s16x8*)&KsB[(cb * 16 + lr) * 128 + ((dc * 32 + lc * 8) ^ sw)];
          sacc[cb] = __builtin_amdgcn_mfma_f32_16x16x32_bf16(kf, qf[dc], sacc[cb], 0, 0, 0);
        }
      __builtin_amdgcn_s_setprio(0);

      if (kt == qt) {  // diagonal tile: causal mask (lane-local q)
        const int qrow = qbase + lr;
#pragma unroll
        for (int cb = 0; cb < 4; ++cb)
#pragma unroll
          for (int r = 0; r < 4; ++r)
            if (kv0 + cb * 16 + lc * 4 + r > qrow) sacc[cb][r] = -1e30f;
      }

      // row max: in-lane over 16, then across the 4 lc-groups
      float rm = sacc[0][0];
#pragma unroll
      for (int cb = 0; cb < 4; ++cb)
#pragma unroll
        for (int r = 0; r < 4; ++r)
          if (cb | r) rm = fmaxf(rm, sacc[cb][r]);
      rm = fmaxf(rm, __shfl_xor(rm, 16, 64));
      rm = fmaxf(rm, __shfl_xor(rm, 32, 64));

      if (!__all(rm <= mrow + 8.f)) {  // defer-max (THR=8)
        const float mnew = fmaxf(mrow, rm);
        const float resc = exp2f(mrow - mnew);
        mrow = mnew;
#pragma unroll
        for (int r = 0; r < 4; ++r) {
          // oacc rows live at q=lc*4+r; fetch resc from a lane with lr==lc*4+r
          const float rr = __shfl(resc, (l & 48) | (((l >> 4) & 3) * 4 + r), 64);
          osum[r] *= rr;
#pragma unroll
          for (int db = 0; db < 8; ++db) oacc[db][r] *= rr;
        }
      }

      // P = exp2(S - m), pack to bf16, store natural slot order (pitch-17 rows)
#pragma unroll
      for (int cb = 0; cb < 4; ++cb) {
        const float p0 = exp2f(sacc[cb][0] - mrow);
        const float p1 = exp2f(sacc[cb][1] - mrow);
        const float p2 = exp2f(sacc[cb][2] - mrow);
        const float p3 = exp2f(sacc[cb][3] - mrow);
        uint2 u;
        u.x = cvt_pk_bf16(p0, p1);
        u.y = cvt_pk_bf16(p2, p3);
        Pb[w][lr][4 * cb + lc] = u;
      }

      // PV: O += P[16][64] * V[64][128]; ones-column accumulates row sums
      __builtin_amdgcn_s_setprio(1);
#pragma unroll
      for (int kk = 0; kk < 2; ++kk) {
        const uint2 plo = Pb[w][lr][8 * kk + 2 * lc];
        const uint2 phi = Pb[w][lr][8 * kk + 2 * lc + 1];
        union { uint2 u2[2]; s16x8 v; } pu;
        pu.u2[0] = plo; pu.u2[1] = phi;
        const s16x8 pf = pu.v;
#pragma unroll
        for (int db = 0; db < 8; ++db) {
          const s16x8 vf = *(const s16x8*)&VsB[(db * 16 + lr) * 64 + ((kk * 32 + lc * 8) ^ sw)];
          oacc[db] = __builtin_amdgcn_mfma_f32_16x16x32_bf16(pf, vf, oacc[db], 0, 0, 0);
        }
        osum = __builtin_amdgcn_mfma_f32_16x16x32_bf16(pf, ones, osum, 0, 0, 0);
      }
      __builtin_amdgcn_s_setprio(0);
      __builtin_amdgcn_sched_barrier(0);
      __builtin_amdgcn_s_barrier();   // all waves done reading buf before reuse
    }

#pragma unroll
    for (int r = 0; r < 4; ++r) {
      const float inv = 1.0f / osum[r];
      const size_t orow = (size_t)b * 2048 + qbase + lc * 4 + r;
#pragma unroll
      for (int db = 0; db < 8; ++db)
        attn_out[orow * 2048 + h * 128 + db * 16 + lr] = f2bf(oacc[db][r] * inv);
    }
  }
}

// ---------------- launch ----------------

extern "C" void kernel_launch(void* const* d_in, const int* in_sizes, int n_in,
                              void* d_out, int out_size, void* d_ws, size_t ws_size,
                              hipStream_t stream) {
  const float* x    = (const float*)d_in[0];
  const float* cosb = (const float*)d_in[1];
  const float* sinb = (const float*)d_in[2];
  const float* wq   = (const float*)d_in[3];
  const float* wk   = (const float*)d_in[4];
  const float* wv   = (const float*)d_in[5];
  const float* wo   = (const float*)d_in[6];
  float* out = (float*)d_out;

  char* ws = (char*)d_ws;
  short* xb    = (short*)(ws);                 // [4096][2048] bf16 (dead after gemm1)
  short* vtb   = (short*)(ws);                 // reuse: [2][512][2048] bf16 (4MB)
  short* kswzb = (short*)(ws + 4194304);       // reuse: [2][4][2048][128] bf16 (4MB)
  short* wqkvT = (short*)(ws + 16777216);      // [3072][2048] bf16
  short* woT   = (short*)(ws + 29360128);      // [2048][2048] bf16
  short* qkvb  = (short*)(ws + 37748736);      // [4096][3072] bf16
  short* attnb = (short*)(ws + 62914560);      // [4096][2048] bf16

  cvt_f32_bf16<<<8192, 256, 0, stream>>>(x, xb, 8388608);
  transpose_cvt<<<dim3(64, 64), 256, 0, stream>>>(wq, wqkvT, 2048, 2048);
  transpose_cvt<<<dim3(16, 64), 256, 0, stream>>>(wk, wqkvT + 2048 * 2048, 2048, 512);
  transpose_cvt<<<dim3(16, 64), 256, 0, stream>>>(wv, wqkvT + 2560 * 2048, 2048, 512);
  transpose_cvt<<<dim3(64, 64), 256, 0, stream>>>(wo, woT, 2048, 2048);

  gemm_bt<true><<<dim3(32, 24), 256, 0, stream>>>(xb, wqkvT, qkvb, 4096, 3072, 2048);
  rope_kernel<<<20480, 256, 0, stream>>>(qkvb, kswzb, cosb, sinb);
  transpose_v<<<dim3(64, 16, 2), 256, 0, stream>>>(qkvb, vtb);
  flash_attn<<<dim3(16, 16, 2), 256, 0, stream>>>(qkvb, kswzb, vtb, attnb);
  gemm_bt<false><<<dim3(32, 16), 256, 0, stream>>>(attnb, woT, out, 4096, 2048, 2048);
}